// Round 2
// baseline (450.471 us; speedup 1.0000x reference)
//
#include <hip/hip_runtime.h>
#include <math.h>

#define N_ATOMS  50000
#define N_NBRS   32
#define N_BASIS  128
#define N_FILT   128
#define N_GAUSS  25
#define RCUT     5.0f
#define TT       2048      // filter table nodes
#define AMM      16        // atoms per block (= MFMA M)
#define PI_F     3.14159265358979323846f

typedef short bf16x8 __attribute__((ext_vector_type(8)));
typedef float f32x4  __attribute__((ext_vector_type(4)));

__device__ __forceinline__ float ssp(float x) {
  return fmaxf(x, 0.0f) + log1pf(__expf(-fabsf(x))) - 0.69314718055994531f;
}
__device__ __forceinline__ unsigned short f2b(float x) {  // f32 -> bf16 RNE
  union { float f; unsigned u; } v; v.f = x;
  unsigned r = v.u + 0x7fffu + ((v.u >> 16) & 1u);
  return (unsigned short)(r >> 16);
}
__device__ __forceinline__ float b2f(unsigned short b) {
  return __uint_as_float(((unsigned)b) << 16);
}

// ---- prep 1: filter-table nodes wnode[i][f] = (W(r_i)*fcut(r_i)), r_i = i*RCUT/(TT-1)
__global__ void build_wnode_kernel(const float* __restrict__ fw1,
                                   const float* __restrict__ fb1,
                                   const float* __restrict__ fw2,
                                   const float* __restrict__ fb2,
                                   float* __restrict__ wnode,
                                   float* __restrict__ out) {
  const int i = blockIdx.x;
  const int f = threadIdx.x;
  if (i == 0 && f == 0) out[0] = 0.0f;   // zero output accumulator each call
  const float r = (float)i * (RCUT / (float)(TT - 1));
  const float delta = RCUT / (float)(N_GAUSS - 1);
  const float coeff = -0.5f / (delta * delta);
  float h = fb1[f];
  #pragma unroll
  for (int g = 0; g < N_GAUSS; ++g) {
    const float d = r - (float)g * delta;
    h = fmaf(__expf(coeff * d * d), fw1[g * N_FILT + f], h);
  }
  h = ssp(h);
  __shared__ float hl[N_FILT];
  hl[f] = h;
  __syncthreads();
  float w = fb2[f];
  for (int j = 0; j < N_FILT; j += 4) {
    const float4 hv = *reinterpret_cast<const float4*>(&hl[j]);
    w = fmaf(hv.x, fw2[(j + 0) * N_FILT + f], w);
    w = fmaf(hv.y, fw2[(j + 1) * N_FILT + f], w);
    w = fmaf(hv.z, fw2[(j + 2) * N_FILT + f], w);
    w = fmaf(hv.w, fw2[(j + 3) * N_FILT + f], w);
  }
  const float fc = (r < RCUT) ? 0.5f * (__cosf(r * PI_F / RCUT) + 1.0f) : 0.0f;
  wnode[i * N_FILT + f] = w * fc;
}

// ---- prep 2: pack lerp pairs table2[i][f] = (w_i, w_{i+1}-w_i)
__global__ void pack_table_kernel(const float* __restrict__ wnode,
                                  float2* __restrict__ table2) {
  const int i = blockIdx.x;
  const int f = threadIdx.x;
  if (i >= TT - 1) return;
  const float w0 = wnode[i * N_FILT + f];
  const float w1 = wnode[(i + 1) * N_FILT + f];
  table2[i * N_FILT + f] = make_float2(w0, w1 - w0);
}

// ---- prep 3: bf16 transposed weights BT[col][k] (contiguous along K)
__global__ void prep_weights_kernel(const float* __restrict__ w1,
                                    const float* __restrict__ w2,
                                    const float* __restrict__ in2f,
                                    const float* __restrict__ mw1,
                                    unsigned short* __restrict__ w1bt,
                                    unsigned short* __restrict__ w2bt,
                                    unsigned short* __restrict__ in2fbt,
                                    unsigned short* __restrict__ mw1bt) {
  const int c = blockIdx.x;    // output column (0..127)
  const int i = threadIdx.x;   // input row   (0..127)
  w1bt[c * 128 + i]   = f2b(w1[i * 128 + c]);
  w2bt[c * 128 + i]   = f2b(w2[i * 128 + c]);
  in2fbt[c * 128 + i] = f2b(in2f[i * 128 + c]);
  if (c < 64) mw1bt[c * 128 + i] = f2b(mw1[i * 64 + c]);
}

// ---- y = embed[Z] @ in2f  ->  bf16 [N, 128]  (MFMA)
__global__ void __launch_bounds__(128)
compute_y_kernel(const int* __restrict__ Z,
                 const float* __restrict__ embed,
                 const unsigned short* __restrict__ in2fbt,
                 unsigned short* __restrict__ y_bf) {
  const int f  = threadIdx.x;
  const int a0 = blockIdx.x * AMM;
  const int wv = f >> 6;
  const int l  = f & 63;
  __shared__ unsigned short sX[AMM * 128];
  #pragma unroll
  for (int m = 0; m < AMM; ++m) {
    sX[m * 128 + f] = f2b(embed[(size_t)Z[a0 + m] * N_BASIS + f]);
  }
  __syncthreads();
  const int rc = l & 15;        // A-row / B-col / C-col
  const int qk = l >> 4;        // k quarter
  f32x4 acc[4];
  #pragma unroll
  for (int t = 0; t < 4; ++t) acc[t] = (f32x4){0.f, 0.f, 0.f, 0.f};
  #pragma unroll
  for (int k0 = 0; k0 < 128; k0 += 32) {
    const bf16x8 af = *reinterpret_cast<const bf16x8*>(&sX[rc * 128 + k0 + qk * 8]);
    #pragma unroll
    for (int t = 0; t < 4; ++t) {
      const int c = wv * 64 + t * 16 + rc;
      const bf16x8 bf = *reinterpret_cast<const bf16x8*>(&in2fbt[c * 128 + k0 + qk * 8]);
      acc[t] = __builtin_amdgcn_mfma_f32_16x16x32_bf16(af, bf, acc[t], 0, 0, 0);
    }
  }
  #pragma unroll
  for (int t = 0; t < 4; ++t) {
    const int c = wv * 64 + t * 16 + rc;
    #pragma unroll
    for (int r = 0; r < 4; ++r) {
      const int atom = qk * 4 + r;
      y_bf[(size_t)(a0 + atom) * 128 + c] = f2b(acc[t][r]);
    }
  }
}

// ---- main fused kernel: cfconv + f2out + residual + MLP + sum
__global__ void __launch_bounds__(128)
schnet_main_kernel(const float* __restrict__ dR,
                   const int* __restrict__ Z,
                   const int* __restrict__ nbr,
                   const float* __restrict__ embed,
                   const float2* __restrict__ table2,
                   const unsigned short* __restrict__ y_bf,
                   const unsigned short* __restrict__ w1bt, const float* __restrict__ b1,
                   const unsigned short* __restrict__ w2bt, const float* __restrict__ b2,
                   const unsigned short* __restrict__ mw1bt, const float* __restrict__ mb1,
                   const float* __restrict__ mw2, const float* __restrict__ mb2,
                   float* __restrict__ out) {
  const int f  = threadIdx.x;          // channel 0..127
  const int a0 = blockIdx.x * AMM;
  const int wv = f >> 6;
  const int l  = f & 63;
  __shared__ int4 s_pk[AMM * N_NBRS];          // 8 KB: {tab_off, fr, y_off, 0}
  __shared__ unsigned short sA[AMM * 128];     // 4 KB activation ping
  __shared__ unsigned short sB[AMM * 128];     // 4 KB activation pong
  __shared__ int   sZ[AMM];
  __shared__ float sRed[2];

  // -- stage per-pair packs (coalesced) --
  const float scale = (float)(TT - 1) / RCUT;
  for (int t = f; t < AMM * N_NBRS; t += 128) {
    const float r = dR[a0 * N_NBRS + t];
    const int  nb = nbr[a0 * N_NBRS + t];
    const float u = r * scale;
    int i0 = (int)u;
    i0 = min(i0, TT - 2);
    const float fr = u - (float)i0;
    s_pk[t] = make_int4(i0 * (N_FILT * 8), __float_as_int(fr), nb * (N_FILT * 2), 0);
  }
  if (f < AMM) sZ[f] = Z[a0 + f];
  __syncthreads();

  // -- cfconv: agg[m] = sum_k y_bf[nbr] * lerp(table2) --
  float agg[AMM];
  #pragma unroll
  for (int m = 0; m < AMM; ++m) agg[m] = 0.0f;
  const int f8 = f * 8;   // byte offset into float2 table row
  const int f2 = f * 2;   // byte offset into bf16 y row
  for (int k = 0; k < N_NBRS; ++k) {
    #pragma unroll
    for (int m = 0; m < AMM; ++m) {
      const int4 pk = s_pk[m * N_NBRS + k];
      const float2 wd = *reinterpret_cast<const float2*>(
          reinterpret_cast<const char*>(table2) + pk.x + f8);
      const unsigned short yb = *reinterpret_cast<const unsigned short*>(
          reinterpret_cast<const char*>(y_bf) + pk.z + f2);
      const float wvv = fmaf(__int_as_float(pk.y), wd.y, wd.x);
      agg[m] = fmaf(b2f(yb), wvv, agg[m]);
    }
  }
  #pragma unroll
  for (int m = 0; m < AMM; ++m) sA[m * 128 + f] = f2b(agg[m]);
  __syncthreads();

  const int rc = l & 15;
  const int qk = l >> 4;
  const int aoff = rc * 128 + qk * 8;  // A-frag element offset (row-major [16][128])

  // -- f2out layer 1: h1 = ssp(agg @ w1 + b1) --
  f32x4 acc[4];
  #pragma unroll
  for (int t = 0; t < 4; ++t) {
    const float b = b1[wv * 64 + t * 16 + rc];
    acc[t] = (f32x4){b, b, b, b};
  }
  #pragma unroll
  for (int k0 = 0; k0 < 128; k0 += 32) {
    const bf16x8 af = *reinterpret_cast<const bf16x8*>(&sA[aoff + k0]);
    #pragma unroll
    for (int t = 0; t < 4; ++t) {
      const int c = wv * 64 + t * 16 + rc;
      const bf16x8 bf = *reinterpret_cast<const bf16x8*>(&w1bt[c * 128 + k0 + qk * 8]);
      acc[t] = __builtin_amdgcn_mfma_f32_16x16x32_bf16(af, bf, acc[t], 0, 0, 0);
    }
  }
  #pragma unroll
  for (int t = 0; t < 4; ++t) {
    const int c = wv * 64 + t * 16 + rc;
    #pragma unroll
    for (int r = 0; r < 4; ++r) {
      sB[(qk * 4 + r) * 128 + c] = f2b(ssp(acc[t][r]));
    }
  }
  __syncthreads();

  // -- f2out layer 2 + residual: xnew = embed[Z] + (h1 @ w2 + b2) --
  #pragma unroll
  for (int t = 0; t < 4; ++t) {
    const float b = b2[wv * 64 + t * 16 + rc];
    acc[t] = (f32x4){b, b, b, b};
  }
  #pragma unroll
  for (int k0 = 0; k0 < 128; k0 += 32) {
    const bf16x8 af = *reinterpret_cast<const bf16x8*>(&sB[aoff + k0]);
    #pragma unroll
    for (int t = 0; t < 4; ++t) {
      const int c = wv * 64 + t * 16 + rc;
      const bf16x8 bf = *reinterpret_cast<const bf16x8*>(&w2bt[c * 128 + k0 + qk * 8]);
      acc[t] = __builtin_amdgcn_mfma_f32_16x16x32_bf16(af, bf, acc[t], 0, 0, 0);
    }
  }
  #pragma unroll
  for (int t = 0; t < 4; ++t) {
    const int c = wv * 64 + t * 16 + rc;
    #pragma unroll
    for (int r = 0; r < 4; ++r) {
      const int atom = qk * 4 + r;
      const float x = embed[(size_t)sZ[atom] * N_BASIS + c] + acc[t][r];
      sA[atom * 128 + c] = f2b(x);
    }
  }
  __syncthreads();

  // -- MLP layer 1: p = xnew @ mw1 + mb1  (128 -> 64), 2 tiles per wave --
  f32x4 acc2[2];
  #pragma unroll
  for (int t = 0; t < 2; ++t) {
    const float b = mb1[wv * 32 + t * 16 + rc];
    acc2[t] = (f32x4){b, b, b, b};
  }
  #pragma unroll
  for (int k0 = 0; k0 < 128; k0 += 32) {
    const bf16x8 af = *reinterpret_cast<const bf16x8*>(&sA[aoff + k0]);
    #pragma unroll
    for (int t = 0; t < 2; ++t) {
      const int j = wv * 32 + t * 16 + rc;
      const bf16x8 bf = *reinterpret_cast<const bf16x8*>(&mw1bt[j * 128 + k0 + qk * 8]);
      acc2[t] = __builtin_amdgcn_mfma_f32_16x16x32_bf16(af, bf, acc2[t], 0, 0, 0);
    }
  }

  // -- MLP layer 2 (64 -> 1) + global sum --
  float v = 0.0f;
  #pragma unroll
  for (int t = 0; t < 2; ++t) {
    const int j = wv * 32 + t * 16 + rc;
    const float c2 = mw2[j];
    #pragma unroll
    for (int r = 0; r < 4; ++r) {
      v = fmaf(ssp(acc2[t][r]), c2, v);
    }
  }
  #pragma unroll
  for (int o = 1; o < 64; o <<= 1) v += __shfl_xor(v, o, 64);
  if (l == 0) sRed[wv] = v;
  __syncthreads();
  if (f == 0) {
    atomicAdd(out, 20.0f * (sRed[0] + sRed[1] + (float)AMM * mb2[0]));
  }
}

extern "C" void kernel_launch(void* const* d_in, const int* in_sizes, int n_in,
                              void* d_out, int out_size, void* d_ws, size_t ws_size,
                              hipStream_t stream) {
  const float* dR    = (const float*)d_in[0];
  const int*   Z     = (const int*)  d_in[1];
  const int*   nbr   = (const int*)  d_in[2];
  const float* embed = (const float*)d_in[3];
  const float* fw1   = (const float*)d_in[4];
  const float* fb1   = (const float*)d_in[5];
  const float* fw2   = (const float*)d_in[6];
  const float* fb2   = (const float*)d_in[7];
  const float* in2f  = (const float*)d_in[8];
  const float* w1    = (const float*)d_in[9];
  const float* b1    = (const float*)d_in[10];
  const float* w2    = (const float*)d_in[11];
  const float* b2    = (const float*)d_in[12];
  const float* mw1   = (const float*)d_in[13];
  const float* mb1   = (const float*)d_in[14];
  const float* mw2   = (const float*)d_in[15];
  const float* mb2   = (const float*)d_in[16];
  float* out = (float*)d_out;

  char* ws = (char*)d_ws;
  float2*         table2 = (float2*)ws;                               // 2 MB
  float*          wnode  = (float*)(ws + (size_t)2 * 1024 * 1024);    // 1 MB
  unsigned short* y_bf   = (unsigned short*)(ws + (size_t)3 * 1024 * 1024);   // 12.8 MB
  char* wbase = ws + (size_t)16 * 1024 * 1024;
  unsigned short* w1bt   = (unsigned short*)(wbase);                  // 32 KB
  unsigned short* w2bt   = (unsigned short*)(wbase + 32 * 1024);      // 32 KB
  unsigned short* in2fbt = (unsigned short*)(wbase + 64 * 1024);      // 32 KB
  unsigned short* mw1bt  = (unsigned short*)(wbase + 96 * 1024);      // 16 KB

  build_wnode_kernel<<<TT, 128, 0, stream>>>(fw1, fb1, fw2, fb2, wnode, out);
  pack_table_kernel<<<TT - 1, 128, 0, stream>>>(wnode, table2);
  prep_weights_kernel<<<128, 128, 0, stream>>>(w1, w2, in2f, mw1,
                                               w1bt, w2bt, in2fbt, mw1bt);
  compute_y_kernel<<<N_ATOMS / AMM, 128, 0, stream>>>(Z, embed, in2fbt, y_bf);
  schnet_main_kernel<<<N_ATOMS / AMM, 128, 0, stream>>>(dR, Z, nbr, embed,
      table2, y_bf, w1bt, b1, w2bt, b2, mw1bt, mb1, mw2, mb2, out);
}

// Round 3
// 197.389 us; speedup vs baseline: 2.2822x; 2.2822x over previous
//
#include <hip/hip_runtime.h>
#include <math.h>

#define N_ATOMS  50000
#define N_NBRS   32
#define N_GAUSS  25
#define RCUT     5.0f
#define TT       1024      // filter table nodes (lerp)
#define MAXZ     100
#define PI_F     3.14159265358979323846f

typedef unsigned int   uint_t;
typedef unsigned short ushort_t;
typedef _Float16 f16;
typedef f16   f16x8 __attribute__((ext_vector_type(8)));
typedef float f32x4 __attribute__((ext_vector_type(4)));

__device__ __forceinline__ float ssp(float x) {
  return fmaxf(x, 0.0f) + log1pf(__expf(-fabsf(x))) - 0.69314718055994531f;
}
__device__ __forceinline__ float f16_lo(uint_t u) {
  return (float)__builtin_bit_cast(f16, (ushort_t)(u & 0xFFFFu));
}
__device__ __forceinline__ float f16_hi(uint_t u) {
  return (float)__builtin_bit_cast(f16, (ushort_t)(u >> 16));
}
__device__ __forceinline__ ushort_t f2h(float x) {
  return __builtin_bit_cast(ushort_t, (f16)x);
}
// swizzled element offset into a [16][128] f16 LDS tile (8-elem chunk XOR row)
__device__ __forceinline__ int swz(int m, int e) {
  return m * 128 + ((((e >> 3) ^ m) & 15) << 3) + (e & 7);
}

// ---- prep 1: W(r_i)*fcut(r_i) at TT nodes, f32 ----
__global__ void build_wnode_kernel(const float* __restrict__ fw1,
                                   const float* __restrict__ fb1,
                                   const float* __restrict__ fw2,
                                   const float* __restrict__ fb2,
                                   float* __restrict__ wnode,
                                   float* __restrict__ out) {
  const int i = blockIdx.x;
  const int f = threadIdx.x;
  if (i == 0 && f == 0) out[0] = 0.0f;   // re-zero output accumulator every launch
  const float r = (float)i * (RCUT / (float)(TT - 1));
  const float delta = RCUT / (float)(N_GAUSS - 1);
  const float coeff = -0.5f / (delta * delta);
  float h = fb1[f];
  #pragma unroll
  for (int g = 0; g < N_GAUSS; ++g) {
    const float d = r - (float)g * delta;
    h = fmaf(__expf(coeff * d * d), fw1[g * 128 + f], h);
  }
  h = ssp(h);
  __shared__ float hl[128];
  hl[f] = h;
  __syncthreads();
  float w = fb2[f];
  for (int j = 0; j < 128; j += 4) {
    const float4 hv = *reinterpret_cast<const float4*>(&hl[j]);
    w = fmaf(hv.x, fw2[(j + 0) * 128 + f], w);
    w = fmaf(hv.y, fw2[(j + 1) * 128 + f], w);
    w = fmaf(hv.z, fw2[(j + 2) * 128 + f], w);
    w = fmaf(hv.w, fw2[(j + 3) * 128 + f], w);
  }
  const float fc = (r < RCUT) ? 0.5f * (__cosf(r * PI_F / RCUT) + 1.0f) : 0.0f;
  wnode[i * 128 + f] = w * fc;
}

// ---- prep 2: pack lerp pairs as f16x2: tab[i][f] = (w_i, w_{i+1}-w_i) ----
__global__ void pack_table_kernel(const float* __restrict__ wnode,
                                  uint_t* __restrict__ tab) {
  const int i = blockIdx.x;
  const int f = threadIdx.x;
  const float w0 = wnode[i * 128 + f];
  const int i1 = min(i + 1, TT - 1);
  const float dw = wnode[i1 * 128 + f] - w0;
  tab[i * 128 + f] = (uint_t)f2h(w0) | ((uint_t)f2h(dw) << 16);
}

// ---- prep 3: ytab[z] = embed[z] @ in2f  (only 100 distinct rows!), f16 ----
__global__ void build_ytab_kernel(const float* __restrict__ embed,
                                  const float* __restrict__ in2f,
                                  f16* __restrict__ ytab) {
  const int z = blockIdx.x;
  const int f = threadIdx.x;
  __shared__ float xs[128];
  xs[f] = embed[z * 128 + f];
  __syncthreads();
  float acc = 0.0f;
  for (int i = 0; i < 128; i += 4) {
    const float4 xv = *reinterpret_cast<const float4*>(&xs[i]);
    acc = fmaf(xv.x, in2f[(i + 0) * 128 + f], acc);
    acc = fmaf(xv.y, in2f[(i + 1) * 128 + f], acc);
    acc = fmaf(xv.z, in2f[(i + 2) * 128 + f], acc);
    acc = fmaf(xv.w, in2f[(i + 3) * 128 + f], acc);
  }
  ytab[z * 128 + f] = (f16)acc;
}

// ---- prep 4: f16 transposed dense weights, contiguous along K ----
__global__ void prep_weights_kernel(const float* __restrict__ w1,
                                    const float* __restrict__ w2,
                                    const float* __restrict__ mw1,
                                    f16* __restrict__ w1ht,
                                    f16* __restrict__ w2ht,
                                    f16* __restrict__ mw1ht) {
  const int c = blockIdx.x;    // output column
  const int i = threadIdx.x;   // input row
  w1ht[c * 128 + i] = (f16)w1[i * 128 + c];
  w2ht[c * 128 + i] = (f16)w2[i * 128 + c];
  if (c < 64) mw1ht[c * 128 + i] = (f16)mw1[i * 64 + c];
}

// ---- main fused kernel ----
__global__ void __launch_bounds__(128)
schnet_main_kernel(const float* __restrict__ dR,
                   const int* __restrict__ Z,
                   const int* __restrict__ nbr,
                   const float* __restrict__ embed,
                   const uint_t* __restrict__ tab,
                   const f16* __restrict__ ytab,
                   const f16* __restrict__ w1ht, const float* __restrict__ b1,
                   const f16* __restrict__ w2ht, const float* __restrict__ b2,
                   const f16* __restrict__ mw1ht, const float* __restrict__ mb1,
                   const float* __restrict__ mw2, const float* __restrict__ mb2,
                   float* __restrict__ out) {
  const int f  = threadIdx.x;
  const int a0 = blockIdx.x * 16;
  const int wv = f >> 6;
  const int l  = f & 63;
  __shared__ int2 s_pk[16 * N_NBRS];   // 4 KB: {tab_off|fr12<<20, ytab_off}
  __shared__ f16  sA[16 * 128];        // 4 KB swizzled activations
  __shared__ f16  sB[16 * 128];        // 4 KB swizzled activations
  __shared__ int   sZ[16];
  __shared__ float sRed[2];

  // -- stage per-pair packed offsets (coalesced dR/nbr; Z gather is L2-hit) --
  const float scale = (float)(TT - 1) / RCUT;
  for (int t = f; t < 16 * N_NBRS; t += 128) {
    const float r = dR[a0 * N_NBRS + t];
    const int  nb = nbr[a0 * N_NBRS + t];
    const float u = r * scale;
    int i0 = (int)u;
    i0 = min(i0, TT - 2);
    const int fr12 = (int)((u - (float)i0) * 4096.0f);
    const int z = Z[nb];
    s_pk[t] = make_int2((i0 << 9) | (fr12 << 20), z << 8);
  }
  if (f < 16) sZ[f] = Z[a0 + f];
  __syncthreads();

  // -- cfconv: wave wv owns atoms m0..m0+7; each lane owns channels 2l,2l+1 --
  const int m0 = wv * 8;
  const char* tabc = (const char*)tab;
  const char* ytc  = (const char*)ytab;
  float2 agg[8];
  #pragma unroll
  for (int j = 0; j < 8; ++j) agg[j] = make_float2(0.0f, 0.0f);

  uint2 twA[8]; uint_t ybA[8]; float frA[8];
  uint2 twB[8]; uint_t ybB[8]; float frB[8];

#define ISSUE(S, kk) { \
    _Pragma("unroll") \
    for (int j = 0; j < 8; ++j) { \
      const int2 p = s_pk[(m0 + j) * N_NBRS + (kk)]; \
      const uint_t w = (uint_t)p.x; \
      tw##S[j] = *(const uint2*)(tabc + (w & 0xFFFFFu) + l * 8); \
      yb##S[j] = *(const uint_t*)(ytc + p.y + l * 4); \
      fr##S[j] = (float)(w >> 20) * (1.0f / 4096.0f); \
    } }

#define CONSUME(S) { \
    _Pragma("unroll") \
    for (int j = 0; j < 8; ++j) { \
      const float frv = fr##S[j]; \
      const uint2  T = tw##S[j]; \
      const uint_t Y = yb##S[j]; \
      const float wa = fmaf(frv, f16_hi(T.x), f16_lo(T.x)); \
      const float wb = fmaf(frv, f16_hi(T.y), f16_lo(T.y)); \
      agg[j].x = fmaf(f16_lo(Y), wa, agg[j].x); \
      agg[j].y = fmaf(f16_hi(Y), wb, agg[j].y); \
    } }

  ISSUE(A, 0)
  for (int kb = 0; kb < 16; ++kb) {
    ISSUE(B, 2 * kb + 1)
    CONSUME(A)
    if (kb < 15) { ISSUE(A, 2 * kb + 2) }
    CONSUME(B)
  }
#undef ISSUE
#undef CONSUME

  // write agg -> sA (swizzled, f16 pair = one 4B store)
  #pragma unroll
  for (int j = 0; j < 8; ++j) {
    const int m = m0 + j;
    const int off = swz(m, 2 * l);   // even within-chunk pos -> 4B aligned
    const uint_t pk = (uint_t)f2h(agg[j].x) | ((uint_t)f2h(agg[j].y) << 16);
    *(uint_t*)&sA[off] = pk;
  }
  __syncthreads();

  const int rc = l & 15;
  const int qk = l >> 4;
#define AFRAG(SRC, k0) (*(const f16x8*)&SRC[rc * 128 + (((((k0) >> 3) + qk) ^ rc) & 15) * 8])

  // -- f2out layer 1: h1 = ssp(agg @ w1 + b1) --
  f32x4 acc[4];
  #pragma unroll
  for (int t = 0; t < 4; ++t) {
    const float b = b1[wv * 64 + t * 16 + rc];
    acc[t] = (f32x4){b, b, b, b};
  }
  #pragma unroll
  for (int k0 = 0; k0 < 128; k0 += 32) {
    const f16x8 af = AFRAG(sA, k0);
    #pragma unroll
    for (int t = 0; t < 4; ++t) {
      const int c = wv * 64 + t * 16 + rc;
      const f16x8 bf = *(const f16x8*)&w1ht[c * 128 + k0 + qk * 8];
      acc[t] = __builtin_amdgcn_mfma_f32_16x16x32_f16(af, bf, acc[t], 0, 0, 0);
    }
  }
  #pragma unroll
  for (int t = 0; t < 4; ++t) {
    const int c = wv * 64 + t * 16 + rc;
    #pragma unroll
    for (int r = 0; r < 4; ++r) {
      sB[swz(qk * 4 + r, c)] = (f16)ssp(acc[t][r]);
    }
  }
  __syncthreads();

  // -- f2out layer 2 + residual: xnew = embed[Z] + (h1 @ w2 + b2) --
  #pragma unroll
  for (int t = 0; t < 4; ++t) {
    const float b = b2[wv * 64 + t * 16 + rc];
    acc[t] = (f32x4){b, b, b, b};
  }
  #pragma unroll
  for (int k0 = 0; k0 < 128; k0 += 32) {
    const f16x8 af = AFRAG(sB, k0);
    #pragma unroll
    for (int t = 0; t < 4; ++t) {
      const int c = wv * 64 + t * 16 + rc;
      const f16x8 bf = *(const f16x8*)&w2ht[c * 128 + k0 + qk * 8];
      acc[t] = __builtin_amdgcn_mfma_f32_16x16x32_f16(af, bf, acc[t], 0, 0, 0);
    }
  }
  __syncthreads();   // all sB reads done before overwriting sA? (sA rewritten below)
  #pragma unroll
  for (int t = 0; t < 4; ++t) {
    const int c = wv * 64 + t * 16 + rc;
    #pragma unroll
    for (int r = 0; r < 4; ++r) {
      const int m = qk * 4 + r;
      const float x = embed[(size_t)sZ[m] * 128 + c] + acc[t][r];
      sA[swz(m, c)] = (f16)x;
    }
  }
  __syncthreads();

  // -- MLP layer 1: 128 -> 64 (2 col-tiles per wave) --
  f32x4 acc2[2];
  #pragma unroll
  for (int t = 0; t < 2; ++t) {
    const float b = mb1[wv * 32 + t * 16 + rc];
    acc2[t] = (f32x4){b, b, b, b};
  }
  #pragma unroll
  for (int k0 = 0; k0 < 128; k0 += 32) {
    const f16x8 af = AFRAG(sA, k0);
    #pragma unroll
    for (int t = 0; t < 2; ++t) {
      const int j = wv * 32 + t * 16 + rc;
      const f16x8 bf = *(const f16x8*)&mw1ht[j * 128 + k0 + qk * 8];
      acc2[t] = __builtin_amdgcn_mfma_f32_16x16x32_f16(af, bf, acc2[t], 0, 0, 0);
    }
  }

  // -- MLP layer 2 (64 -> 1) + global sum --
  float v = 0.0f;
  #pragma unroll
  for (int t = 0; t < 2; ++t) {
    const int j = wv * 32 + t * 16 + rc;
    const float c2 = mw2[j];
    #pragma unroll
    for (int r = 0; r < 4; ++r) {
      v = fmaf(ssp(acc2[t][r]), c2, v);
    }
  }
  #pragma unroll
  for (int o = 1; o < 64; o <<= 1) v += __shfl_xor(v, o, 64);
  if (l == 0) sRed[wv] = v;
  __syncthreads();
  if (f == 0) {
    atomicAdd(out, 20.0f * (sRed[0] + sRed[1] + 16.0f * mb2[0]));
  }
#undef AFRAG
}

extern "C" void kernel_launch(void* const* d_in, const int* in_sizes, int n_in,
                              void* d_out, int out_size, void* d_ws, size_t ws_size,
                              hipStream_t stream) {
  const float* dR    = (const float*)d_in[0];
  const int*   Z     = (const int*)  d_in[1];
  const int*   nbr   = (const int*)  d_in[2];
  const float* embed = (const float*)d_in[3];
  const float* fw1   = (const float*)d_in[4];
  const float* fb1   = (const float*)d_in[5];
  const float* fw2   = (const float*)d_in[6];
  const float* fb2   = (const float*)d_in[7];
  const float* in2f  = (const float*)d_in[8];
  const float* w1    = (const float*)d_in[9];
  const float* b1    = (const float*)d_in[10];
  const float* w2    = (const float*)d_in[11];
  const float* b2    = (const float*)d_in[12];
  const float* mw1   = (const float*)d_in[13];
  const float* mb1   = (const float*)d_in[14];
  const float* mw2   = (const float*)d_in[15];
  const float* mb2   = (const float*)d_in[16];
  float* out = (float*)d_out;

  char* ws = (char*)d_ws;
  float*  wnode = (float*)ws;                              // 512 KB
  uint_t* tab   = (uint_t*)(ws + (size_t)1 * 1024 * 1024); // 512 KB
  f16*    ytab  = (f16*)  (ws + (size_t)2 * 1024 * 1024);  // 25.6 KB
  f16*    w1ht  = (f16*)  (ws + (size_t)3 * 1024 * 1024);  // 32 KB
  f16*    w2ht  = (f16*)  (ws + (size_t)3 * 1024 * 1024 + 64 * 1024);
  f16*    mw1ht = (f16*)  (ws + (size_t)3 * 1024 * 1024 + 128 * 1024);

  build_wnode_kernel<<<TT, 128, 0, stream>>>(fw1, fb1, fw2, fb2, wnode, out);
  pack_table_kernel<<<TT, 128, 0, stream>>>(wnode, tab);
  build_ytab_kernel<<<MAXZ, 128, 0, stream>>>(embed, in2f, ytab);
  prep_weights_kernel<<<128, 128, 0, stream>>>(w1, w2, mw1, w1ht, w2ht, mw1ht);
  schnet_main_kernel<<<N_ATOMS / 16, 128, 0, stream>>>(dR, Z, nbr, embed,
      tab, ytab, w1ht, b1, w2ht, b2, mw1ht, mb1, mw2, mb2, out);
}